// Round 5
// baseline (1282.366 us; speedup 1.0000x reference)
//
#include <hip/hip_runtime.h>
#include <hip/hip_fp16.h>

#define B_ 16
#define T_ 256
#define D_ 128
#define H_ 256
#define HP 264   // LDS h row pitch in halves (528 B: odd 16B multiple -> even bank spread)

typedef _Float16 f16;
typedef __attribute__((ext_vector_type(8))) _Float16 f16x8;
typedef __attribute__((ext_vector_type(4))) _Float16 f16x4;
typedef __attribute__((ext_vector_type(4))) float f32x4;

__device__ __forceinline__ float fast_rcp(float x) {
#if __has_builtin(__builtin_amdgcn_rcpf)
    return __builtin_amdgcn_rcpf(x);
#else
    return 1.0f / x;
#endif
}
__device__ __forceinline__ float sigmoid_f(float x) {
    return fast_rcp(1.0f + __expf(-x));
}
__device__ __forceinline__ float tanh_f(float x) {
    float e = __expf(2.0f * x);
    return 1.0f - 2.0f * fast_rcp(1.0f + e);
}

// ---- weight prep: Whh f32 [768][256] -> MFMA B-fragment order f16 ----
// layout idx = (((wv*2+u)*3+g)*8+kc)*64 + lane ; each cell = f16x8 of
// Whh[col = g*256 + wv*32 + u*16 + (lane&15)][k = kc*32 + (lane>>4)*8 .. +8]
__global__ void k_wprep(const float* __restrict__ wa, const float* __restrict__ wb,
                        f16x8* __restrict__ oa, f16x8* __restrict__ ob) {
    int idx = blockIdx.x * 256 + threadIdx.x;   // [0, 98304) : 2 mats x 49152
    const float* src = (idx < 49152) ? wa : wb;
    f16x8* dst = (idx < 49152) ? oa : ob;
    int i = idx & 49151;
    int l = i & 63;
    int kc = (i >> 6) & 7;
    int rest = i >> 9;        // (wv*2+u)*3+g
    int g = rest % 3;
    int uu = rest / 3;        // wv*2+u in [0,16)
    int col = g * 256 + (uu >> 1) * 32 + (uu & 1) * 16 + (l & 15);
    int k0 = kc * 32 + (l >> 4) * 8;
    const float* s = src + col * 256 + k0;
    f16x8 v;
#pragma unroll
    for (int q = 0; q < 8; ++q) v[q] = (f16)s[q];
    dst[i] = v;
}

// ---- mask precompute: pos[b][s] = first t with targets[b,t]==s (else T) ----
__global__ void k_pos_init(int* __restrict__ pos) {
    pos[blockIdx.x * 256 + threadIdx.x] = T_;
}
__global__ void k_pos_scan(const int* __restrict__ tgt, int* __restrict__ pos) {
    int i = blockIdx.x * 256 + threadIdx.x;
    int b = i >> 8, t = i & 255;
    int s = tgt[i] & 255;
    atomicMin(&pos[(b << 8) + s], t);
}

// ---- enc_in = inputs @ W_enc^T + b_enc ----
__global__ __launch_bounds__(256) void k_encA(const float* __restrict__ in,
                                              const float* __restrict__ W,
                                              const float* __restrict__ bias,
                                              float* __restrict__ out) {
    int bt0 = blockIdx.x * 8;
    int a = threadIdx.x;
    float bv = bias[a];
    float acc[8];
#pragma unroll
    for (int tt = 0; tt < 8; ++tt) acc[tt] = bv;
    const float* wr = W + a * D_;
    for (int k = 0; k < D_; k += 4) {
        float4 w4 = *(const float4*)(wr + k);
#pragma unroll
        for (int tt = 0; tt < 8; ++tt) {
            float4 x4 = *(const float4*)(in + (bt0 + tt) * D_ + k);
            acc[tt] += w4.x * x4.x + w4.y * x4.y + w4.z * x4.z + w4.w * x4.w;
        }
    }
#pragma unroll
    for (int tt = 0; tt < 8; ++tt) out[(bt0 + tt) * H_ + a] = acc[tt];
}

// ---- x_proj -> f16 fragment layout, bhh folded into r,z gates ----
__global__ __launch_bounds__(256) void k_proj3(const float* __restrict__ in,
                                               const float* __restrict__ W,
                                               const float* __restrict__ bih,
                                               const float* __restrict__ bhh,
                                               const int* __restrict__ tgt,
                                               f16* __restrict__ gout) {
    int bt0 = blockIdx.x * 8;
    int b = bt0 >> 8;
    int a = threadIdx.x;
    const float* rp[8];
#pragma unroll
    for (int tt = 0; tt < 8; ++tt) {
        int t = (bt0 & 255) + tt;
        int tsrc = t;
        if (tgt) tsrc = tgt[(b << 8) + ((t + 255) & 255)] & 255; // roll(targets,1)
        rp[tt] = in + ((b << 8) + tsrc) * H_;
    }
    float acc0[8], acc1[8], acc2[8];
    float b0 = bih[a] + bhh[a];               // r gate: fold bhh
    float b1 = bih[a + 256] + bhh[a + 256];   // z gate: fold bhh
    float b2 = bih[a + 512];                  // n gate: bhh applied inside GRU
#pragma unroll
    for (int tt = 0; tt < 8; ++tt) { acc0[tt] = b0; acc1[tt] = b1; acc2[tt] = b2; }
    const float* w0 = W + a * H_;
    const float* w1 = W + (a + 256) * H_;
    const float* w2 = W + (a + 512) * H_;
    for (int k = 0; k < H_; k += 4) {
        float4 a4 = *(const float4*)(w0 + k);
        float4 b4 = *(const float4*)(w1 + k);
        float4 c4 = *(const float4*)(w2 + k);
#pragma unroll
        for (int tt = 0; tt < 8; ++tt) {
            float4 x4 = *(const float4*)(rp[tt] + k);
            acc0[tt] += a4.x * x4.x + a4.y * x4.y + a4.z * x4.z + a4.w * x4.w;
            acc1[tt] += b4.x * x4.x + b4.y * x4.y + b4.z * x4.z + b4.w * x4.w;
            acc2[tt] += c4.x * x4.x + c4.y * x4.y + c4.z * x4.z + c4.w * x4.w;
        }
    }
    // fragment store: idx = ((t*8+wv)*6 + (u*3+g))*256 + (b>>2)*64 + (a&15)*4 + (b&3)
    int wv = a >> 5, u = (a >> 4) & 1, nn = a & 15;
    int lpos = (b >> 2) * 64 + nn * 4 + (b & 3);
#pragma unroll
    for (int tt = 0; tt < 8; ++tt) {
        int t = (bt0 & 255) + tt;
        int base = (t * 8 + wv) * 6 * 256 + lpos;
        gout[base + (u * 3 + 0) * 256] = (f16)acc0[tt];
        gout[base + (u * 3 + 1) * 256] = (f16)acc1[tt];
        gout[base + (u * 3 + 2) * 256] = (f16)acc2[tt];
    }
}

// ---- single-row projection (q / k), no bias ----
__global__ __launch_bounds__(256) void k_proj1(const float* __restrict__ in,
                                               const float* __restrict__ W,
                                               float* __restrict__ out) {
    int bt0 = blockIdx.x * 8;
    int a = threadIdx.x;
    float acc[8];
#pragma unroll
    for (int tt = 0; tt < 8; ++tt) acc[tt] = 0.f;
    const float* w0 = W + a * H_;
    for (int k = 0; k < H_; k += 4) {
        float4 w4 = *(const float4*)(w0 + k);
#pragma unroll
        for (int tt = 0; tt < 8; ++tt) {
            float4 x4 = *(const float4*)(in + (bt0 + tt) * H_ + k);
            acc[tt] += w4.x * x4.x + w4.y * x4.y + w4.z * x4.z + w4.w * x4.w;
        }
    }
#pragma unroll
    for (int tt = 0; tt < 8; ++tt) out[(bt0 + tt) * H_ + a] = acc[tt];
}

// ---- MFMA GRU: ONE block, all 16 batches. 512 threads = 8 waves. ----
// Per step: G[16,768] = h[16,256] @ Whh^T via mfma_f32_16x16x32_f16.
// Wave wv owns gate columns j in [wv*32, wv*32+32) of each gate block:
// 6 N-tiles (u in {0,1} x gates r,z,n) x 8 K-chunks = 48 B-frags = 192 VGPRs
// held as MFMA operands. A-frags (h) read from LDS ping-pong buffer.
// D layout (m89-verified): col = lane&15 (unit), row = (lane>>4)*4+reg (batch).
// Gates are lane-local: no shuffles, no partial sums.
__global__ __launch_bounds__(512)
void k_gru(const f16x8* __restrict__ Wp,   // prepped weights (k_wprep)
           const f16* __restrict__ gi,     // [T][8wv][6f][256] halves (k_proj3)
           const float* __restrict__ bhh,  // [768]; only n-gate slice used here
           const float* __restrict__ h0,   // [16][256] f32 or null (zeros)
           float* __restrict__ out,        // [16][256][256] f32
           float* __restrict__ hT) {       // [16][256] f32 or null
    __shared__ __align__(16) f16 shh[2][16 * HP];
    const int tid = threadIdx.x, wv = tid >> 6, l = tid & 63;
    const int n = l & 15, kg = l >> 4;

    // B-fragments: loop-invariant MFMA operands -> stay register-resident
    f16x8 wfr[2][3][8];
#pragma unroll
    for (int u = 0; u < 2; ++u)
#pragma unroll
        for (int g = 0; g < 3; ++g)
#pragma unroll
            for (int kc = 0; kc < 8; ++kc)
                wfr[u][g][kc] = Wp[((((wv * 2 + u) * 3 + g) << 3) + kc) * 64 + l];

    const float bhn0 = bhh[512 + wv * 32 + n];
    const float bhn1 = bhh[512 + wv * 32 + 16 + n];

    // init h into LDS buffer 0 (each (batch m, unit j) written exactly once)
#pragma unroll
    for (int u = 0; u < 2; ++u) {
        const int j = wv * 32 + u * 16 + n;
#pragma unroll
        for (int r = 0; r < 4; ++r) {
            const int m = kg * 4 + r;
            shh[0][m * HP + j] = (f16)(h0 ? h0[m * H_ + j] : 0.f);
        }
    }
    __syncthreads();

    const f16* gp = gi + wv * 6 * 256 + l * 4;
    f16x4 gc[6];
#pragma unroll
    for (int f = 0; f < 6; ++f) gc[f] = *(const f16x4*)(gp + f * 256);

    for (int t = 0; t < T_; ++t) {
        const int cur = t & 1;
        f32x4 acc[2][3];
#pragma unroll
        for (int u = 0; u < 2; ++u)
#pragma unroll
            for (int g = 0; g < 3; ++g) acc[u][g] = (f32x4){0.f, 0.f, 0.f, 0.f};

        // A-frags: lane reads h[batch = l&15][k = kc*32 + (l>>4)*8 .. +8]
        const f16* hb = &shh[cur][n * HP + kg * 8];
#pragma unroll
        for (int kc = 0; kc < 8; ++kc) {
            f16x8 af = *(const f16x8*)(hb + kc * 32);
#pragma unroll
            for (int u = 0; u < 2; ++u)
#pragma unroll
                for (int g = 0; g < 3; ++g)
                    acc[u][g] = __builtin_amdgcn_mfma_f32_16x16x32_f16(
                        af, wfr[u][g][kc], acc[u][g], 0, 0, 0);
        }

        // gates: lane-local per (batch row, unit col)
#pragma unroll
        for (int u = 0; u < 2; ++u) {
            const int j = wv * 32 + u * 16 + n;
            const float bn = u ? bhn1 : bhn0;
#pragma unroll
            for (int r = 0; r < 4; ++r) {
                const int m = kg * 4 + r;
                float hp = (float)shh[cur][m * HP + j];
                float rr = sigmoid_f((float)gc[u * 3 + 0][r] + acc[u][0][r]);
                float zz = sigmoid_f((float)gc[u * 3 + 1][r] + acc[u][1][r]);
                float nv = tanh_f((float)gc[u * 3 + 2][r] + rr * (acc[u][2][r] + bn));
                float hn = (1.f - zz) * nv + zz * hp;
                out[(m * T_ + t) * H_ + j] = hn;
                shh[cur ^ 1][m * HP + j] = (f16)hn;
                if (hT && t == T_ - 1) hT[m * H_ + j] = hn;
            }
        }

        // single-buffered gi reload for t+1: in flight across the barrier,
        // consumed next gate phase (waitcnt auto-inserted before use)
        if (t < T_ - 1) {
            const f16* gq = gp + (t + 1) * (8 * 6 * 256);
#pragma unroll
            for (int f = 0; f < 6; ++f) gc[f] = *(const f16x4*)(gq + f * 256);
        }
        // LDS-only barrier: do NOT drain vmcnt (keeps gi loads + out stores in flight)
        asm volatile("s_waitcnt lgkmcnt(0)" ::: "memory");
        __builtin_amdgcn_s_barrier();
    }
}

// ---- transpose k[b][s][a] -> kT[b][a][s] ----
__global__ __launch_bounds__(256) void k_transpose(const float* __restrict__ k_,
                                                   float* __restrict__ kT) {
    __shared__ float tile[64][65];
    int blk = blockIdx.x;
    int b = blk >> 4;
    int ti = (blk >> 2) & 3;
    int tj = blk & 3;
    int lane = threadIdx.x & 63;
    int ty = threadIdx.x >> 6;
    const float* kb = k_ + b * (T_ * H_);
    for (int r = ty; r < 64; r += 4)
        tile[r][lane] = kb[(ti * 64 + r) * H_ + tj * 64 + lane];
    __syncthreads();
    float* kTb = kT + b * (T_ * H_);
    for (int r = ty; r < 64; r += 4)
        kTb[(tj * 64 + r) * T_ + ti * 64 + lane] = tile[lane][r];
}

// ---- logits[b,t,s] = mask ? v . tanh(q[b,t,:]+k[b,s,:]) : -1e9 ----
__global__ __launch_bounds__(256) void k_scores(const float* __restrict__ q,
                                                const float* __restrict__ kT,
                                                const float* __restrict__ v,
                                                const int* __restrict__ pos,
                                                float* __restrict__ out) {
    __shared__ float sq[4][256];
    __shared__ float sv[256];
    int blk = blockIdx.x;
    int b = blk >> 6;
    int t0 = (blk & 63) * 4;
    int s = threadIdx.x;
    sv[s] = v[s];
#pragma unroll
    for (int tt = 0; tt < 4; ++tt)
        sq[tt][s] = q[((b << 8) + t0 + tt) * H_ + s];
    __syncthreads();
    int ps = pos[(b << 8) + s];
    float acc[4] = {0.f, 0.f, 0.f, 0.f};
    const float* kTb = kT + b * (T_ * H_);
    for (int a = 0; a < H_; ++a) {
        float kv = kTb[a * T_ + s];
        float va = sv[a];
#pragma unroll
        for (int tt = 0; tt < 4; ++tt) {
            float th = tanh_f(sq[tt][a] + kv);
            acc[tt] += va * th;
        }
    }
#pragma unroll
    for (int tt = 0; tt < 4; ++tt) {
        int t = t0 + tt;
        out[((b << 8) + t) * T_ + s] = (t <= ps) ? acc[tt] : -1.0e9f;
    }
}

extern "C" void kernel_launch(void* const* d_in, const int* in_sizes, int n_in,
                              void* d_out, int out_size, void* d_ws, size_t ws_size,
                              hipStream_t stream) {
    (void)in_sizes; (void)n_in; (void)out_size; (void)ws_size;
    const float* inputs   = (const float*)d_in[0];
    const int* targets    = (const int*)d_in[1];
    const float* W_enc   = (const float*)d_in[2];
    const float* b_enc   = (const float*)d_in[3];
    const float* enc_Wih = (const float*)d_in[4];
    const float* enc_Whh = (const float*)d_in[5];
    const float* enc_bih = (const float*)d_in[6];
    const float* enc_bhh = (const float*)d_in[7];
    const float* dec_Wih = (const float*)d_in[8];
    const float* dec_Whh = (const float*)d_in[9];
    const float* dec_bih = (const float*)d_in[10];
    const float* dec_bhh = (const float*)d_in[11];
    const float* Wq = (const float*)d_in[12];
    const float* Wk = (const float*)d_in[13];
    const float* v  = (const float*)d_in[14];
    float* out = (float*)d_out;

    float* ws = (float*)d_ws;
    float* enc_in  = ws;                        // 1,048,576 f
    f16*   gi      = (f16*)(ws + 1048576);      // 3,145,728 halves (1,572,864 f) enc then dec
    float* enc_out = ws + 2621440;              // 1,048,576 f
    float* dec_out = ws + 3670016;              // 1,048,576 f
    f16x8* wpe     = (f16x8*)(ws + 4718592);    // 49,152 f16x8 (98,304 f)
    f16x8* wpd     = (f16x8*)(ws + 4816896);    // 98,304 f
    float* hT      = ws + 4915200;              // 4,096 f
    int*   pos     = (int*)(ws + 4919296);      // 4,096 i
    float* q  = enc_in;    // alias: enc_in dead after dec proj3
    float* kk = (float*)gi; // alias: gi dead after dec GRU
    float* kT = enc_out;   // alias: enc_out dead after proj1(Wk)

    k_wprep<<<384, 256, 0, stream>>>(enc_Whh, dec_Whh, wpe, wpd);
    k_pos_init<<<16, 256, 0, stream>>>(pos);
    k_pos_scan<<<16, 256, 0, stream>>>(targets, pos);
    k_encA<<<512, 256, 0, stream>>>(inputs, W_enc, b_enc, enc_in);
    k_proj3<<<512, 256, 0, stream>>>(enc_in, enc_Wih, enc_bih, enc_bhh, nullptr, gi);
    k_gru<<<1, 512, 0, stream>>>(wpe, gi, enc_bhh, nullptr, enc_out, hT);
    k_proj3<<<512, 256, 0, stream>>>(enc_in, dec_Wih, dec_bih, dec_bhh, targets, gi);
    k_gru<<<1, 512, 0, stream>>>(wpd, gi, dec_bhh, hT, dec_out, nullptr);
    k_proj1<<<512, 256, 0, stream>>>(dec_out, Wq, q);
    k_proj1<<<512, 256, 0, stream>>>(enc_out, Wk, kk);
    k_transpose<<<256, 256, 0, stream>>>(kk, kT);
    k_scores<<<1024, 256, 0, stream>>>(q, kT, v, pos, out);
}